// Round 6
// baseline (2935.326 us; speedup 1.0000x reference)
//
#include <hip/hip_runtime.h>
#include <cstdint>
#include <cstddef>

#define BB 8
#define NN 8192
#define CC 64
#define MM 2048
#define KK 32

typedef float vfloat2 __attribute__((ext_vector_type(2)));

__device__ __forceinline__ float sqdist_exact(float x, float y, float z,
                                              float cx, float cy, float cz) {
    // Replicate numpy/JAX f32: (x-c)**2 summed ((dx2+dy2)+dz2), no FMA contraction.
    float dx = __fsub_rn(x, cx);
    float dy = __fsub_rn(y, cy);
    float dz = __fsub_rn(z, cz);
    return __fadd_rn(__fadd_rn(__fmul_rn(dx, dx), __fmul_rn(dy, dy)),
                     __fmul_rn(dz, dz));
}

// ---- single u64 DPP wave64 max ladder (value<<32 | ~idx): 6 stages ----
// row_shr:N = 0x110|N, row_bcast15 = 0x142, row_bcast31 = 0x143.
// bound_ctrl=true -> invalid source lanes read 0; all real keys are > 0 (low
// word ~idx >= 0xFFFFE000), so shifted-in zeros never win.
template <int CTRL>
__device__ __forceinline__ unsigned long long dpp_max_u64(unsigned long long key) {
    int lo = (int)(unsigned)key;
    int hi = (int)(unsigned)(key >> 32);
    int slo = __builtin_amdgcn_update_dpp(0, lo, CTRL, 0xF, 0xF, true);
    int shi = __builtin_amdgcn_update_dpp(0, hi, CTRL, 0xF, 0xF, true);
    unsigned long long o = ((unsigned long long)(unsigned)shi << 32) | (unsigned)slo;
    return o > key ? o : key;
}

// Octile boundaries of N(0,1): equal-mass 8-way split per dimension.
__device__ __forceinline__ int octile(float v) {
    return (v > -1.1503494f) + (v > -0.6744898f) + (v > -0.3186394f) + (v > 0.0f) +
           (v > 0.3186394f) + (v > 0.6744898f) + (v > 1.1503494f);
}

// 9-bit Morton interleave of three 3-bit coords: consecutive bin ids are
// spatially compact (a thread's 2 bins / a wave's 128 bins form sub-cubes).
__device__ __forceinline__ int morton9(int bx, int by, int bz) {
    int m = (bz & 1) | ((bz & 2) << 2) | ((bz & 4) << 4);
    m |= ((by & 1) << 1) | ((by & 2) << 3) | ((by & 4) << 5);
    m |= ((bx & 1) << 2) | ((bx & 2) << 4) | ((bx & 4) << 6);
    return m;
}

// ---------------- FPS: one block per batch, 256 threads / 4 waves ----------------
// r6: attack the measured ~2050-cycle serial floor (issue cuts r3/r5 were
// neutral): 4 waves instead of 8 (halves barrier reconvergence skew and
// cross-wave reduce width), single 6-stage u64 DPP ladder (vs 12-stage
// split ladders, ~-80cy chain), packed xyz LDS array (centroid = one
// ds_read_b96 window). Exact bbox pruning + LDS sfps + no global ops in
// the loop are kept from the verified r3/r5 structure.
__global__ __launch_bounds__(256) void fps_kernel(const float* __restrict__ x,
                                                  int* __restrict__ fps_idx) {
#pragma clang fp contract(off)
    const int b = blockIdx.x;
    const int tid = threadIdx.x;
    const int lane = tid & 63;
    const float* xb = x + (size_t)b * 3 * NN;
    int* fps_store = fps_idx + b * MM;

    __shared__ float spk[NN * 3];  // packed xyz, original-index order (96 KB)
    __shared__ int sidx[NN];       // binned order -> original index (32 KB)
    __shared__ int hist[512];
    __shared__ int scanb[512];
    __shared__ int sfps[MM];       // selected indices, dumped at the end (8 KB)
    __shared__ unsigned long long red3[3];  // triple-buffered atomic-max slot

    const vfloat2* gx = (const vfloat2*)xb;
    const vfloat2* gy = (const vfloat2*)(xb + NN);
    const vfloat2* gz = (const vfloat2*)(xb + 2 * NN);

    // ---- load global -> packed LDS (float2 global reads, 32 pts/thread) ----
#pragma unroll
    for (int p = 0; p < 16; ++p) {
        const int e = tid + p * 256;  // float2 slot; covers points 2e, 2e+1
        vfloat2 ax = gx[e];
        vfloat2 ay = gy[e];
        vfloat2 az = gz[e];
        spk[6 * e + 0] = ax.x;
        spk[6 * e + 1] = ay.x;
        spk[6 * e + 2] = az.x;
        spk[6 * e + 3] = ax.y;
        spk[6 * e + 4] = ay.y;
        spk[6 * e + 5] = az.y;
    }
    hist[tid] = 0;
    hist[tid + 256] = 0;
    if (tid < 3) red3[tid] = 0ull;
    __syncthreads();

    // ---- histogram over 512 morton-octile bins ----
    int mybin[32];
#pragma unroll
    for (int p = 0; p < 32; ++p) {
        const int i = tid + p * 256;
        int bn = morton9(octile(spk[3 * i]), octile(spk[3 * i + 1]),
                         octile(spk[3 * i + 2]));
        mybin[p] = bn;
        atomicAdd(&hist[bn], 1);
    }
    __syncthreads();
    // ---- exclusive prefix sum over 512 bins (Hillis-Steele, 2 elems/thread) ----
    int own0 = hist[tid];
    int own1 = hist[tid + 256];
    scanb[tid] = own0;
    scanb[tid + 256] = own1;
    __syncthreads();
    for (int off = 1; off < 512; off <<= 1) {
        int a0 = (tid >= off) ? scanb[tid - off] : 0;
        int a1 = (tid + 256 >= off) ? scanb[tid + 256 - off] : 0;
        __syncthreads();
        scanb[tid] += a0;
        scanb[tid + 256] += a1;
        __syncthreads();
    }
    hist[tid] = scanb[tid] - own0;          // per-bin scatter cursor
    hist[tid + 256] = scanb[tid + 256] - own1;
    __syncthreads();
    // ---- scatter original indices into binned order ----
#pragma unroll
    for (int p = 0; p < 32; ++p) {
        const int i = tid + p * 256;
        int pos = atomicAdd(&hist[mybin[p]], 1);
        sidx[pos] = i;
    }
    __syncthreads();

    // ---- gather this thread's 32-point chunk (packed pairs) + bbox ----
    vfloat2 px[16], py[16], pz[16], dist[16];
    int idxr[32];
#pragma unroll
    for (int p = 0; p < 16; ++p) {
        const int j0 = sidx[tid * 32 + 2 * p];
        const int j1 = sidx[tid * 32 + 2 * p + 1];
        idxr[2 * p] = j0;
        idxr[2 * p + 1] = j1;
        px[p] = (vfloat2){spk[3 * j0], spk[3 * j1]};
        py[p] = (vfloat2){spk[3 * j0 + 1], spk[3 * j1 + 1]};
        pz[p] = (vfloat2){spk[3 * j0 + 2], spk[3 * j1 + 2]};
        dist[p] = (vfloat2){INFINITY, INFINITY};
    }
    float blx = fminf(px[0].x, px[0].y), bhx = fmaxf(px[0].x, px[0].y);
    float bly = fminf(py[0].x, py[0].y), bhy = fmaxf(py[0].x, py[0].y);
    float blz = fminf(pz[0].x, pz[0].y), bhz = fmaxf(pz[0].x, pz[0].y);
#pragma unroll
    for (int p = 1; p < 16; ++p) {
        blx = fminf(blx, fminf(px[p].x, px[p].y));
        bhx = fmaxf(bhx, fmaxf(px[p].x, px[p].y));
        bly = fminf(bly, fminf(py[p].x, py[p].y));
        bhy = fmaxf(bhy, fmaxf(py[p].x, py[p].y));
        blz = fminf(blz, fminf(pz[p].x, pz[p].y));
        bhz = fmaxf(bhz, fmaxf(pz[p].x, pz[p].y));
    }

    float cmax = INFINITY;  // exact max of this chunk's current dists
    int cidx = idxr[0];     // smallest original index achieving cmax
    int far = 0;
    for (int t = 0; t < MM; ++t) {
        if (tid == 0) {
            sfps[t] = far;                 // LDS only: no vmcnt drain at barrier
            red3[(t + 1) % 3] = 0ull;      // pre-reset next slot (its previous
        }                                  // readers all passed barrier t-1)
        const float cx = spk[3 * far];     // one b96-mergeable LDS window
        const float cy = spk[3 * far + 1];
        const float cz = spk[3 * far + 2];

        // Lower bound on d^2(c, bbox) via clamp (v_med3). 0.999f margin >>
        // f32 rounding slack (~1.5e-6 rel) between this bound and the exact
        // per-point pipeline, so skipping is guaranteed a value-exact no-op.
        float qx = cx - fminf(fmaxf(cx, blx), bhx);
        float qy = cy - fminf(fmaxf(cy, bly), bhy);
        float qz = cz - fminf(fmaxf(cz, blz), bhz);
        float bound = (qx * qx + qy * qy) + qz * qz;
        const bool act = !(bound * 0.999f >= cmax);
        if (act) {  // per-lane predication; compiler wave-skips via execz
            const vfloat2 cx2 = {cx, cx};
            const vfloat2 cy2 = {cy, cy};
            const vfloat2 cz2 = {cz, cz};
            float mv = -1.0f;
#pragma unroll
            for (int p = 0; p < 16; ++p) {
                vfloat2 dx = px[p] - cx2;   // v_pk_add_f32
                vfloat2 dy = py[p] - cy2;
                vfloat2 dz = pz[p] - cz2;
                vfloat2 m1 = dx * dx;       // v_pk_mul_f32
                vfloat2 m2 = dy * dy;
                vfloat2 m3 = dz * dz;
                vfloat2 s = (m1 + m2) + m3; // matches reference order
                vfloat2 nd;
                nd.x = fminf(dist[p].x, s.x);
                nd.y = fminf(dist[p].y, s.y);
                dist[p] = nd;
                mv = fmaxf(fmaxf(mv, nd.x), nd.y);  // -> v_max3_f32
            }
            // smallest ORIGINAL index among chunk maxima (binned != idx order)
            int mi = 0x7FFFFFFF;
#pragma unroll
            for (int p = 0; p < 16; ++p) {
                mi = min(mi, (dist[p].x == mv) ? idxr[2 * p] : 0x7FFFFFFF);
                mi = min(mi, (dist[p].y == mv) ? idxr[2 * p + 1] : 0x7FFFFFFF);
            }
            cmax = mv;
            cidx = mi;
        }

        // ---- single u64 (value, ~idx) DPP max ladder: 6 stages ----
        unsigned long long key =
            ((unsigned long long)__float_as_uint(cmax) << 32) |
            (unsigned)(~(unsigned)cidx);
        key = dpp_max_u64<0x111>(key);  // row_shr:1
        key = dpp_max_u64<0x112>(key);  // row_shr:2
        key = dpp_max_u64<0x114>(key);  // row_shr:4
        key = dpp_max_u64<0x118>(key);  // row_shr:8
        key = dpp_max_u64<0x142>(key);  // row_bcast15
        key = dpp_max_u64<0x143>(key);  // row_bcast31 -> lane 63 has wave max
        if (lane == 63) atomicMax(&red3[t % 3], key);  // ds_max_u64, 4 writers
        __syncthreads();
        far = (int)(~(unsigned)red3[t % 3]);  // one 8B LDS broadcast read
    }
    __syncthreads();
    // coalesced dump of the selected indices
    for (int t = tid; t < MM; t += 256) fps_store[t] = sfps[t];
}

// ---------------- transform: g[b][n][o] = sum_c W[o][c] * f[b][c][n] ----------------
__global__ __launch_bounds__(256) void transform_kernel(const float* __restrict__ feature,
                                                        const float* __restrict__ weight,
                                                        float* __restrict__ g) {
    __shared__ float Wl[64 * 64];
    const int tid = threadIdx.x;
    for (int k = tid; k < 64 * 64; k += 256) Wl[k] = weight[k];
    __syncthreads();

    const int P = blockIdx.x * 256 + tid;  // global point slot
    const int b = P >> 13;                 // / 8192
    const int n = P & (NN - 1);
    const float* fb = feature + (size_t)b * CC * NN + n;

    float fr[64];
#pragma unroll
    for (int c = 0; c < 64; ++c) fr[c] = fb[(size_t)c * NN];

    float* go = g + ((size_t)b << 19) + (size_t)n * 64;
    for (int o = 0; o < 64; o += 4) {
        const float* w0 = &Wl[o * 64];
        const float* w1 = w0 + 64;
        const float* w2 = w0 + 128;
        const float* w3 = w0 + 192;
        float a0 = 0.f, a1 = 0.f, a2 = 0.f, a3 = 0.f;
#pragma unroll
        for (int c = 0; c < 64; c += 4) {
            float4 v0 = *(const float4*)(w0 + c);
            float4 v1 = *(const float4*)(w1 + c);
            float4 v2 = *(const float4*)(w2 + c);
            float4 v3 = *(const float4*)(w3 + c);
            a0 += v0.x * fr[c] + v0.y * fr[c + 1] + v0.z * fr[c + 2] + v0.w * fr[c + 3];
            a1 += v1.x * fr[c] + v1.y * fr[c + 1] + v1.z * fr[c + 2] + v1.w * fr[c + 3];
            a2 += v2.x * fr[c] + v2.y * fr[c + 1] + v2.z * fr[c + 2] + v2.w * fr[c + 3];
            a3 += v3.x * fr[c] + v3.y * fr[c + 1] + v3.z * fr[c + 2] + v3.w * fr[c + 3];
        }
        float4 r;
        r.x = a0; r.y = a1; r.z = a2; r.w = a3;
        *(float4*)(go + o) = r;
    }
}

// ---------------- merged ball-query + gather-max: one wave per query ----------------
// bq phase finds up to 32 in-radius indices (kept in LDS, no global round
// trip) and emits x_out; gather phase max-reduces g over those indices
// (lane = output channel). Removes the sub_idx workspace traffic and one
// kernel launch gap.
__global__ __launch_bounds__(256) void bqgather_kernel(const float* __restrict__ x,
                                                       const int* __restrict__ fps_idx,
                                                       const float* __restrict__ g,
                                                       float* __restrict__ xout,
                                                       float* __restrict__ fout) {
    const float R2 = (float)(0.4 * 0.4);  // match python double product -> f32 cast
    __shared__ int sidl[4][KK];           // per-wave found indices
    int gw = (int)((blockIdx.x * 256 + threadIdx.x) >> 6);
    const int lane = threadIdx.x & 63;
    const int wvl = threadIdx.x >> 6;
    gw = __builtin_amdgcn_readfirstlane(gw);
    const int b = gw >> 11;
    const int m = gw & (MM - 1);
    const float* xb = x + (size_t)b * 3 * NN;

    const int ctr = fps_idx[gw];
    const float cx = xb[ctr];
    const float cy = xb[NN + ctr];
    const float cz = xb[2 * NN + ctr];

    int found = 0;
    int first = 0;
    float mx = -INFINITY, my = -INFINITY, mz = -INFINITY;

    for (int base = 0; base < NN; base += 64) {
        const int i = base + lane;
        const float xx = xb[i];
        const float yy = xb[NN + i];
        const float zz = xb[2 * NN + i];
        const float d2 = sqdist_exact(xx, yy, zz, cx, cy, cz);
        const bool q = d2 < R2;
        const unsigned long long mask = __ballot(q);
        if (q) {
            int pos = found + (int)__popcll(mask & ((1ull << lane) - 1ull));
            if (pos < KK) {
                sidl[wvl][pos] = i;
                mx = fmaxf(mx, xx);
                my = fmaxf(my, yy);
                mz = fmaxf(mz, zz);
            }
        }
        if (found == 0 && mask != 0ull) first = base + (int)__builtin_ctzll(mask);
        found += (int)__popcll(mask);
        if (found >= KK) break;
    }
    if (found < KK) {
        if (lane < KK - found) sidl[wvl][found + lane] = first;  // pad with first found
    }
#pragma unroll
    for (int off = 32; off >= 1; off >>= 1) {
        mx = fmaxf(mx, __shfl_xor(mx, off, 64));
        my = fmaxf(my, __shfl_xor(my, off, 64));
        mz = fmaxf(mz, __shfl_xor(mz, off, 64));
    }
    if (lane == 0) {
        xout[(size_t)b * 3 * MM + 0 * MM + m] = mx;
        xout[(size_t)b * 3 * MM + 1 * MM + m] = my;
        xout[(size_t)b * 3 * MM + 2 * MM + m] = mz;
    }
    __syncthreads();  // all waves done writing their sidl row

    // ---- gather-max over g: lane = channel ----
    const float* gb = g + ((size_t)b << 19);
    float acc = -INFINITY;
#pragma unroll
    for (int j = 0; j < KK; ++j) {
        const int id = sidl[wvl][j];
        acc = fmaxf(acc, gb[(size_t)id * 64 + lane]);
    }
    fout[((size_t)b << 17) + ((size_t)lane << 11) + m] = acc;
}

extern "C" void kernel_launch(void* const* d_in, const int* in_sizes, int n_in,
                              void* d_out, int out_size, void* d_ws, size_t ws_size,
                              hipStream_t stream) {
    const float* x = (const float*)d_in[0];        // (8,3,8192)
    const float* feature = (const float*)d_in[1];  // (8,64,8192)
    const float* weight = (const float*)d_in[2];   // (64,64)
    // d_in[3] = num_pool (=2048), hard-coded as MM

    float* out = (float*)d_out;
    float* xout = out;                  // (8,3,2048)
    float* fout = out + BB * 3 * MM;    // (8,64,2048)

    char* ws = (char*)d_ws;
    int* fps_idx = (int*)ws;                                       // 64 KB
    float* g = (float*)(ws + (size_t)BB * MM * 4 + (size_t)BB * MM * KK * 4);  // 16 MB

    fps_kernel<<<BB, 256, 0, stream>>>(x, fps_idx);
    transform_kernel<<<(BB * NN) / 256, 256, 0, stream>>>(feature, weight, g);
    bqgather_kernel<<<(BB * MM * 64) / 256, 256, 0, stream>>>(x, fps_idx, g, xout, fout);
}

// Round 7
// 2651.758 us; speedup vs baseline: 1.1069x; 1.1069x over previous
//
#include <hip/hip_runtime.h>
#include <cstdint>
#include <cstddef>

#define BB 8
#define NN 8192
#define CC 64
#define MM 2048
#define KK 32

typedef float vfloat2 __attribute__((ext_vector_type(2)));

__device__ __forceinline__ float sqdist_exact(float x, float y, float z,
                                              float cx, float cy, float cz) {
    // Replicate numpy/JAX f32: (x-c)**2 summed ((dx2+dy2)+dz2), no FMA contraction.
    float dx = __fsub_rn(x, cx);
    float dy = __fsub_rn(y, cy);
    float dz = __fsub_rn(z, cz);
    return __fadd_rn(__fadd_rn(__fmul_rn(dx, dx), __fmul_rn(dy, dy)),
                     __fmul_rn(dz, dz));
}

// ---- single u64 DPP wave64 max ladder (value<<32 | ~packedidx): 6 stages ----
// row_shr:N = 0x110|N, row_bcast15 = 0x142, row_bcast31 = 0x143.
// bound_ctrl=true -> invalid source lanes read 0; all real keys are > 0 (low
// word >= 0xFC000000), so shifted-in zeros never win.
template <int CTRL>
__device__ __forceinline__ unsigned long long dpp_max_u64(unsigned long long key) {
    int lo = (int)(unsigned)key;
    int hi = (int)(unsigned)(key >> 32);
    int slo = __builtin_amdgcn_update_dpp(0, lo, CTRL, 0xF, 0xF, true);
    int shi = __builtin_amdgcn_update_dpp(0, hi, CTRL, 0xF, 0xF, true);
    unsigned long long o = ((unsigned long long)(unsigned)shi << 32) | (unsigned)slo;
    return o > key ? o : key;
}

// Octile boundaries of N(0,1): equal-mass 8-way split per dimension.
__device__ __forceinline__ int octile(float v) {
    return (v > -1.1503494f) + (v > -0.6744898f) + (v > -0.3186394f) + (v > 0.0f) +
           (v > 0.3186394f) + (v > 0.6744898f) + (v > 1.1503494f);
}

// 9-bit Morton interleave of three 3-bit coords: spatially compact bins.
__device__ __forceinline__ int morton9(int bx, int by, int bz) {
    int m = (bz & 1) | ((bz & 2) << 2) | ((bz & 4) << 4);
    m |= ((by & 1) << 1) | ((by & 2) << 3) | ((by & 4) << 5);
    m |= ((bx & 1) << 2) | ((bx & 2) << 4) | ((bx & 4) << 6);
    return m;
}

// Shared memory: fps layout unioned with transform's weight tile (merged kernel).
union FSmem {
    struct {
        float pb[NN * 3];            // binned-order packed xyz (96 KB)
        float db[NN];                // binned-order current min-dist (32 KB)
        unsigned short ib[NN];       // binned-order original index (16 KB)
        int sfps[MM];                // selected orig indices (8 KB)
        int hist[512];
        int scanb[512];
        unsigned long long red3[3];  // triple-buffered atomic-max slot
        int s0slot;                  // binned slot of orig point 0
    } f;
    float Wl[64 * 64];               // transform weight tile (16 KB)
};

// ---------------- merged FPS (blocks 0..7) + transform (blocks 8..135) ----------------
// FPS r7: wave-cooperative update. dist lives in LDS (binned order); per
// iteration each wave ballots its active chunks (bbox prune, exact) and
// updates them 4-chunks-x-16-points per 64-lane pass (critical path O(1)
// passes late in the run, vs O(16-pt body) per-lane before — r6 proved the
// active wave's body IS the serial floor). Owners rescan their 16 dists
// (exec-masked). Reduce key = (dist<<32)|~(orig<<13|slot): tie-break stays
// smallest ORIG index (bit-exact), slot gives the centroid lookup. One
// barrier/iter + r5-verified ladder/atomic tail. Transform blocks run
// concurrently on otherwise-idle CUs (fps occupies only 8 of 256).
__global__ __launch_bounds__(512) void fps_transform_kernel(
        const float* __restrict__ x, int* __restrict__ fps_idx,
        const float* __restrict__ feature, const float* __restrict__ weight,
        float* __restrict__ g) {
    __shared__ FSmem sm;
    const int tid = threadIdx.x;

    if (blockIdx.x >= BB) {
        // ---------------- transform: g[b][n][o] = sum_c W[o][c]*f[b][c][n] ----------------
        for (int k = tid; k < 64 * 64; k += 512) sm.Wl[k] = weight[k];
        __syncthreads();
        const int P = (blockIdx.x - BB) * 512 + tid;  // global point slot
        const int b = P >> 13;
        const int n = P & (NN - 1);
        const float* fb = feature + (size_t)b * CC * NN + n;
        float fr[64];
#pragma unroll
        for (int c = 0; c < 64; ++c) fr[c] = fb[(size_t)c * NN];
        float* go = g + ((size_t)b << 19) + (size_t)n * 64;
        for (int o = 0; o < 64; o += 4) {
            const float* w0 = &sm.Wl[o * 64];
            const float* w1 = w0 + 64;
            const float* w2 = w0 + 128;
            const float* w3 = w0 + 192;
            float a0 = 0.f, a1 = 0.f, a2 = 0.f, a3 = 0.f;
#pragma unroll
            for (int c = 0; c < 64; c += 4) {
                float4 v0 = *(const float4*)(w0 + c);
                float4 v1 = *(const float4*)(w1 + c);
                float4 v2 = *(const float4*)(w2 + c);
                float4 v3 = *(const float4*)(w3 + c);
                a0 += v0.x * fr[c] + v0.y * fr[c + 1] + v0.z * fr[c + 2] + v0.w * fr[c + 3];
                a1 += v1.x * fr[c] + v1.y * fr[c + 1] + v1.z * fr[c + 2] + v1.w * fr[c + 3];
                a2 += v2.x * fr[c] + v2.y * fr[c + 1] + v2.z * fr[c + 2] + v2.w * fr[c + 3];
                a3 += v3.x * fr[c] + v3.y * fr[c + 1] + v3.z * fr[c + 2] + v3.w * fr[c + 3];
            }
            float4 r;
            r.x = a0; r.y = a1; r.z = a2; r.w = a3;
            *(float4*)(go + o) = r;
        }
        return;
    }

    {
#pragma clang fp contract(off)
        const int b = blockIdx.x;
        const int lane = tid & 63;
        const int wv = tid >> 6;
        const float* xb = x + (size_t)b * 3 * NN;
        int* fps_store = fps_idx + b * MM;

        const vfloat2* gx2 = (const vfloat2*)xb;
        const vfloat2* gy2 = (const vfloat2*)(xb + NN);
        const vfloat2* gz2 = (const vfloat2*)(xb + 2 * NN);

        vfloat2 ax[8], ay[8], az[8];
#pragma unroll
        for (int p = 0; p < 8; ++p) {
            const int e = tid + p * 512;  // float2 slot; covers points 2e, 2e+1
            ax[p] = gx2[e];
            ay[p] = gy2[e];
            az[p] = gz2[e];
        }
        sm.f.hist[tid] = 0;
        if (tid < 3) sm.f.red3[tid] = 0ull;
        __syncthreads();

        // ---- histogram over 512 morton-octile bins (from registers) ----
        int mybin[16];
#pragma unroll
        for (int p = 0; p < 8; ++p) {
            const int b0 = morton9(octile(ax[p].x), octile(ay[p].x), octile(az[p].x));
            const int b1 = morton9(octile(ax[p].y), octile(ay[p].y), octile(az[p].y));
            mybin[2 * p] = b0;
            mybin[2 * p + 1] = b1;
            atomicAdd(&sm.f.hist[b0], 1);
            atomicAdd(&sm.f.hist[b1], 1);
        }
        __syncthreads();
        // ---- exclusive prefix sum (Hillis-Steele, 512 threads == 512 bins) ----
        int own = sm.f.hist[tid];
        sm.f.scanb[tid] = own;
        __syncthreads();
        for (int off = 1; off < 512; off <<= 1) {
            int add = (tid >= off) ? sm.f.scanb[tid - off] : 0;
            __syncthreads();
            sm.f.scanb[tid] += add;
            __syncthreads();
        }
        sm.f.hist[tid] = sm.f.scanb[tid] - own;  // per-bin scatter cursor
        __syncthreads();
        // ---- scatter coords + orig idx into binned order ----
#pragma unroll
        for (int p = 0; p < 8; ++p) {
            const int i0 = 2 * (tid + p * 512);
            int pos0 = atomicAdd(&sm.f.hist[mybin[2 * p]], 1);
            sm.f.pb[3 * pos0] = ax[p].x;
            sm.f.pb[3 * pos0 + 1] = ay[p].x;
            sm.f.pb[3 * pos0 + 2] = az[p].x;
            sm.f.ib[pos0] = (unsigned short)i0;
            if (i0 == 0) sm.f.s0slot = pos0;
            int pos1 = atomicAdd(&sm.f.hist[mybin[2 * p + 1]], 1);
            sm.f.pb[3 * pos1] = ax[p].y;
            sm.f.pb[3 * pos1 + 1] = ay[p].y;
            sm.f.pb[3 * pos1 + 2] = az[p].y;
            sm.f.ib[pos1] = (unsigned short)(i0 + 1);
        }
        __syncthreads();

        // ---- per-chunk bbox + db init + initial packed tie index ----
        float blx = INFINITY, bhx = -INFINITY;
        float bly = INFINITY, bhy = -INFINITY;
        float blz = INFINITY, bhz = -INFINITY;
        int cmi = 0x7FFFFFFF;  // packed (orig<<13)|slot of current arg-max
#pragma unroll
        for (int k = 0; k < 16; ++k) {
            const int s = tid * 16 + k;
            const float X = sm.f.pb[3 * s];
            const float Y = sm.f.pb[3 * s + 1];
            const float Z = sm.f.pb[3 * s + 2];
            blx = fminf(blx, X); bhx = fmaxf(bhx, X);
            bly = fminf(bly, Y); bhy = fmaxf(bhy, Y);
            blz = fminf(blz, Z); bhz = fmaxf(bhz, Z);
            sm.f.db[s] = INFINITY;
            cmi = min(cmi, ((int)sm.f.ib[s] << 13) | s);
        }
        float cmax = INFINITY;
        __syncthreads();

        int forig = 0;
        int fslot = sm.f.s0slot;
        for (int t = 0; t < MM; ++t) {
            if (tid == 0) {
                sm.f.sfps[t] = forig;             // LDS only: no vmcnt at barrier
                sm.f.red3[(t + 1) % 3] = 0ull;    // pre-reset next slot
            }
            const float cx = sm.f.pb[3 * fslot];  // broadcast reads
            const float cy = sm.f.pb[3 * fslot + 1];
            const float cz = sm.f.pb[3 * fslot + 2];

            // Exact bbox lower bound; 0.999f margin >> f32 rounding slack, so
            // skipping is guaranteed a value-exact no-op.
            float qx = cx - fminf(fmaxf(cx, blx), bhx);
            float qy = cy - fminf(fmaxf(cy, bly), bhy);
            float qz = cz - fminf(fmaxf(cz, blz), bhz);
            float bound = (qx * qx + qy * qy) + qz * qz;
            const bool act = !(bound * 0.999f >= cmax);

            // ---- wave-cooperative update: 4 active chunks x 16 pts per pass ----
            unsigned long long m = __ballot(act);
            while (m) {
                int c0 = (int)__builtin_ctzll(m); m &= m - 1;
                int c1 = 64, c2 = 64, c3 = 64;
                if (m) { c1 = (int)__builtin_ctzll(m); m &= m - 1; }
                if (m) { c2 = (int)__builtin_ctzll(m); m &= m - 1; }
                if (m) { c3 = (int)__builtin_ctzll(m); m &= m - 1; }
                const int which = lane >> 4;
                const int cc = which == 0 ? c0 : which == 1 ? c1 : which == 2 ? c2 : c3;
                if (cc != 64) {
                    const int s = ((wv << 6) + cc) * 16 + (lane & 15);
                    const float X = sm.f.pb[3 * s];
                    const float Y = sm.f.pb[3 * s + 1];
                    const float Z = sm.f.pb[3 * s + 2];
                    const float d2 = sqdist_exact(X, Y, Z, cx, cy, cz);
                    const float nd = fminf(sm.f.db[s], d2);
                    sm.f.db[s] = nd;
                }
            }
            // drain wave's LDS ops; stop compiler hoisting the rescan reads
            asm volatile("s_waitcnt lgkmcnt(0)" ::: "memory");
            __builtin_amdgcn_sched_barrier(0);

            // ---- owner rescan (exec-masked to touched chunks) ----
            if (act) {
                float mv = -1.0f;
                vfloat2 dv[8];
#pragma unroll
                for (int k = 0; k < 8; ++k) {
                    dv[k] = ((const vfloat2*)sm.f.db)[tid * 8 + k];
                    mv = fmaxf(fmaxf(mv, dv[k].x), dv[k].y);
                }
                int minc = 0x7FFFFFFF;
#pragma unroll
                for (int k = 0; k < 8; ++k) {
                    const unsigned pr = ((const unsigned*)sm.f.ib)[tid * 8 + k];
                    const int s0 = tid * 16 + 2 * k;
                    const int cand0 = (int)((pr & 0xFFFFu) << 13) | s0;
                    const int cand1 = (int)((pr >> 16) << 13) | (s0 + 1);
                    minc = min(minc, (dv[k].x == mv) ? cand0 : 0x7FFFFFFF);
                    minc = min(minc, (dv[k].y == mv) ? cand1 : 0x7FFFFFFF);
                }
                cmax = mv;
                cmi = minc;
            }

            // ---- single u64 (value, ~packed) DPP max ladder: 6 stages ----
            unsigned long long key =
                ((unsigned long long)__float_as_uint(cmax) << 32) |
                (unsigned)(~(unsigned)cmi);
            key = dpp_max_u64<0x111>(key);  // row_shr:1
            key = dpp_max_u64<0x112>(key);  // row_shr:2
            key = dpp_max_u64<0x114>(key);  // row_shr:4
            key = dpp_max_u64<0x118>(key);  // row_shr:8
            key = dpp_max_u64<0x142>(key);  // row_bcast15
            key = dpp_max_u64<0x143>(key);  // row_bcast31 -> lane 63 has wave max
            if (lane == 63) atomicMax(&sm.f.red3[t % 3], key);  // ds_max_u64, 8 writers
            __syncthreads();
            const unsigned low = ~(unsigned)sm.f.red3[t % 3];   // = (orig<<13)|slot
            forig = (int)(low >> 13);
            fslot = (int)(low & (NN - 1));
        }
        __syncthreads();
        // coalesced dump of the selected indices
        for (int t = tid; t < MM; t += 512) fps_store[t] = sm.f.sfps[t];
    }
}

// ---------------- merged ball-query + gather-max: one wave per query ----------------
__global__ __launch_bounds__(256) void bqgather_kernel(const float* __restrict__ x,
                                                       const int* __restrict__ fps_idx,
                                                       const float* __restrict__ g,
                                                       float* __restrict__ xout,
                                                       float* __restrict__ fout) {
    const float R2 = (float)(0.4 * 0.4);  // match python double product -> f32 cast
    __shared__ int sidl[4][KK];           // per-wave found indices
    int gw = (int)((blockIdx.x * 256 + threadIdx.x) >> 6);
    const int lane = threadIdx.x & 63;
    const int wvl = threadIdx.x >> 6;
    gw = __builtin_amdgcn_readfirstlane(gw);
    const int b = gw >> 11;
    const int m = gw & (MM - 1);
    const float* xb = x + (size_t)b * 3 * NN;

    const int ctr = fps_idx[gw];
    const float cx = xb[ctr];
    const float cy = xb[NN + ctr];
    const float cz = xb[2 * NN + ctr];

    int found = 0;
    int first = 0;
    float mx = -INFINITY, my = -INFINITY, mz = -INFINITY;

    for (int base = 0; base < NN; base += 64) {
        const int i = base + lane;
        const float xx = xb[i];
        const float yy = xb[NN + i];
        const float zz = xb[2 * NN + i];
        const float d2 = sqdist_exact(xx, yy, zz, cx, cy, cz);
        const bool q = d2 < R2;
        const unsigned long long mask = __ballot(q);
        if (q) {
            int pos = found + (int)__popcll(mask & ((1ull << lane) - 1ull));
            if (pos < KK) {
                sidl[wvl][pos] = i;
                mx = fmaxf(mx, xx);
                my = fmaxf(my, yy);
                mz = fmaxf(mz, zz);
            }
        }
        if (found == 0 && mask != 0ull) first = base + (int)__builtin_ctzll(mask);
        found += (int)__popcll(mask);
        if (found >= KK) break;
    }
    if (found < KK) {
        if (lane < KK - found) sidl[wvl][found + lane] = first;  // pad with first found
    }
#pragma unroll
    for (int off = 32; off >= 1; off >>= 1) {
        mx = fmaxf(mx, __shfl_xor(mx, off, 64));
        my = fmaxf(my, __shfl_xor(my, off, 64));
        mz = fmaxf(mz, __shfl_xor(mz, off, 64));
    }
    if (lane == 0) {
        xout[(size_t)b * 3 * MM + 0 * MM + m] = mx;
        xout[(size_t)b * 3 * MM + 1 * MM + m] = my;
        xout[(size_t)b * 3 * MM + 2 * MM + m] = mz;
    }
    __syncthreads();  // all waves done writing their sidl row

    const float* gb = g + ((size_t)b << 19);
    float acc = -INFINITY;
#pragma unroll
    for (int j = 0; j < KK; ++j) {
        const int id = sidl[wvl][j];
        acc = fmaxf(acc, gb[(size_t)id * 64 + lane]);
    }
    fout[((size_t)b << 17) + ((size_t)lane << 11) + m] = acc;
}

extern "C" void kernel_launch(void* const* d_in, const int* in_sizes, int n_in,
                              void* d_out, int out_size, void* d_ws, size_t ws_size,
                              hipStream_t stream) {
    const float* x = (const float*)d_in[0];        // (8,3,8192)
    const float* feature = (const float*)d_in[1];  // (8,64,8192)
    const float* weight = (const float*)d_in[2];   // (64,64)
    // d_in[3] = num_pool (=2048), hard-coded as MM

    float* out = (float*)d_out;
    float* xout = out;                  // (8,3,2048)
    float* fout = out + BB * 3 * MM;    // (8,64,2048)

    char* ws = (char*)d_ws;
    int* fps_idx = (int*)ws;                                       // 64 KB
    float* g = (float*)(ws + (size_t)BB * MM * 4 + (size_t)BB * MM * KK * 4);  // 16 MB

    // blocks 0..7: FPS (one per batch); blocks 8..135: transform (concurrent)
    fps_transform_kernel<<<BB + (BB * NN) / 512, 512, 0, stream>>>(
        x, fps_idx, feature, weight, g);
    bqgather_kernel<<<(BB * MM * 64) / 256, 256, 0, stream>>>(x, fps_idx, g, xout, fout);
}

// Round 8
// 1872.368 us; speedup vs baseline: 1.5677x; 1.4163x over previous
//
#include <hip/hip_runtime.h>
#include <cstdint>
#include <cstddef>

#define BB 8
#define NN 8192
#define CC 64
#define MM 2048
#define KK 32

typedef float vfloat2 __attribute__((ext_vector_type(2)));

__device__ __forceinline__ float sqdist_exact(float x, float y, float z,
                                              float cx, float cy, float cz) {
    // Replicate numpy/JAX f32: (x-c)**2 summed ((dx2+dy2)+dz2), no FMA contraction.
    float dx = __fsub_rn(x, cx);
    float dy = __fsub_rn(y, cy);
    float dz = __fsub_rn(z, cz);
    return __fadd_rn(__fadd_rn(__fmul_rn(dx, dx), __fmul_rn(dy, dy)),
                     __fmul_rn(dz, dz));
}

// ---- DPP wave64 reduce ladder pieces (row_shr:N = 0x110|N, bcast15/31 = 0x142/0x143) ----
// max over nonneg f32 reinterpreted as u32 (identical ordering); bound_ctrl=true -> 0 never wins max.
template <int CTRL>
__device__ __forceinline__ unsigned dpp_max_u32(unsigned v) {
    unsigned s = (unsigned)__builtin_amdgcn_update_dpp(0, (int)v, CTRL, 0xF, 0xF, true);
    return v > s ? v : s;
}
// min over u32 indices; bound_ctrl=false with old=INT_MAX -> invalid lanes never win min.
template <int CTRL>
__device__ __forceinline__ unsigned dpp_min_u32(unsigned v) {
    unsigned s = (unsigned)__builtin_amdgcn_update_dpp(0x7FFFFFFF, (int)v, CTRL, 0xF, 0xF, false);
    return v < s ? v : s;
}

// Octile boundaries of N(0,1): equal-mass 8-way split per dimension.
__device__ __forceinline__ int octile(float v) {
    return (v > -1.1503494f) + (v > -0.6744898f) + (v > -0.3186394f) + (v > 0.0f) +
           (v > 0.3186394f) + (v > 0.6744898f) + (v > 1.1503494f);
}

// 9-bit Morton interleave of three 3-bit coords: consecutive bin ids are
// spatially compact (each wave's 64 bins form a 4x4x4 sub-cube).
__device__ __forceinline__ int morton9(int bx, int by, int bz) {
    int m = (bz & 1) | ((bz & 2) << 2) | ((bz & 4) << 4);
    m |= ((by & 1) << 1) | ((by & 2) << 3) | ((by & 4) << 5);
    m |= ((bx & 1) << 2) | ((bx & 2) << 4) | ((bx & 6) << 4 & 0x40) | ((bx & 4) << 4);
    return m;
}

// NOTE: morton9 above must equal the verified original; keep the exact original:
__device__ __forceinline__ int morton9_ref(int bx, int by, int bz) {
    int m = (bz & 1) | ((bz & 2) << 2) | ((bz & 4) << 4);
    m |= ((by & 1) << 1) | ((by & 2) << 3) | ((by & 4) << 5);
    m |= ((bx & 1) << 2) | ((bx & 2) << 4) | ((bx & 4) << 6);
    return m;
}

// Shared memory: fps layout unioned with transform's weight tile (merged kernel).
union FSmem {
    struct {
        float sx[NN];                // original-index order (centroid lookup)
        float sy[NN];
        float sz[NN];
        int sidx[NN];                // binned order -> original index
        int hist[512];
        int scanb[512];
        int sfps[MM];                // selected indices, dumped at the end
        unsigned long long red3[3];  // triple-buffered atomic-max slot
    } f;
    float Wl[64 * 64];               // transform weight tile (16 KB)
};

// ---------------- merged FPS (blocks 0..7) + transform (blocks 8..135) ----------------
// FPS part is r5's verified structure VERBATIM (1721 us): exact bbox pruning,
// per-lane predicated packed vfloat2 body, unconditional split u32 DPP
// ladders, ds_max_u64 tail, LDS sfps, no global ops in the loop. Transform
// blocks run concurrently on otherwise-idle CUs (fps occupies 8 of 256), so
// transform's ~100+ us hides entirely inside fps's shadow.
__global__ __launch_bounds__(512) void fps_transform_kernel(
        const float* __restrict__ x, int* __restrict__ fps_idx,
        const float* __restrict__ feature, const float* __restrict__ weight,
        float* __restrict__ g) {
    __shared__ FSmem sm;
    const int tid = threadIdx.x;

    if (blockIdx.x >= BB) {
        // ---------------- transform: g[b][n][o] = sum_c W[o][c]*f[b][c][n] ----------------
        for (int k = tid; k < 64 * 64; k += 512) sm.Wl[k] = weight[k];
        __syncthreads();
        const int P = (blockIdx.x - BB) * 512 + tid;  // global point slot
        const int b = P >> 13;
        const int n = P & (NN - 1);
        const float* fb = feature + (size_t)b * CC * NN + n;
        float fr[64];
#pragma unroll
        for (int c = 0; c < 64; ++c) fr[c] = fb[(size_t)c * NN];
        float* go = g + ((size_t)b << 19) + (size_t)n * 64;
        for (int o = 0; o < 64; o += 4) {
            const float* w0 = &sm.Wl[o * 64];
            const float* w1 = w0 + 64;
            const float* w2 = w0 + 128;
            const float* w3 = w0 + 192;
            float a0 = 0.f, a1 = 0.f, a2 = 0.f, a3 = 0.f;
#pragma unroll
            for (int c = 0; c < 64; c += 4) {
                float4 v0 = *(const float4*)(w0 + c);
                float4 v1 = *(const float4*)(w1 + c);
                float4 v2 = *(const float4*)(w2 + c);
                float4 v3 = *(const float4*)(w3 + c);
                a0 += v0.x * fr[c] + v0.y * fr[c + 1] + v0.z * fr[c + 2] + v0.w * fr[c + 3];
                a1 += v1.x * fr[c] + v1.y * fr[c + 1] + v1.z * fr[c + 2] + v1.w * fr[c + 3];
                a2 += v2.x * fr[c] + v2.y * fr[c + 1] + v2.z * fr[c + 2] + v2.w * fr[c + 3];
                a3 += v3.x * fr[c] + v3.y * fr[c + 1] + v3.z * fr[c + 2] + v3.w * fr[c + 3];
            }
            float4 r;
            r.x = a0; r.y = a1; r.z = a2; r.w = a3;
            *(float4*)(go + o) = r;
        }
        return;
    }

    {
#pragma clang fp contract(off)
        const int b = blockIdx.x;
        const int lane = tid & 63;
        const float* xb = x + (size_t)b * 3 * NN;
        int* fps_store = fps_idx + b * MM;

        const vfloat2* gx = (const vfloat2*)xb;
        const vfloat2* gy = (const vfloat2*)(xb + NN);
        const vfloat2* gz = (const vfloat2*)(xb + 2 * NN);

        vfloat2 lx[8], ly[8], lz[8];
#pragma unroll
        for (int p = 0; p < 8; ++p) {
            const int e = tid + p * 512;  // float2 slot; covers points 2e, 2e+1
            lx[p] = gx[e];
            ly[p] = gy[e];
            lz[p] = gz[e];
            ((vfloat2*)sm.f.sx)[e] = lx[p];
            ((vfloat2*)sm.f.sy)[e] = ly[p];
            ((vfloat2*)sm.f.sz)[e] = lz[p];
        }
        sm.f.hist[tid] = 0;
        if (tid < 3) sm.f.red3[tid] = 0ull;
        __syncthreads();

        // ---- histogram over 512 morton-octile bins (from registers) ----
        int mybin[16];
#pragma unroll
        for (int p = 0; p < 8; ++p) {
            int b0 = morton9_ref(octile(lx[p].x), octile(ly[p].x), octile(lz[p].x));
            int b1 = morton9_ref(octile(lx[p].y), octile(ly[p].y), octile(lz[p].y));
            mybin[2 * p] = b0;
            mybin[2 * p + 1] = b1;
            atomicAdd(&sm.f.hist[b0], 1);
            atomicAdd(&sm.f.hist[b1], 1);
        }
        __syncthreads();
        // ---- exclusive prefix sum (Hillis-Steele, 512 threads == 512 bins) ----
        int own = sm.f.hist[tid];
        sm.f.scanb[tid] = own;
        __syncthreads();
        for (int off = 1; off < 512; off <<= 1) {
            int add = (tid >= off) ? sm.f.scanb[tid - off] : 0;
            __syncthreads();
            sm.f.scanb[tid] += add;
            __syncthreads();
        }
        sm.f.hist[tid] = sm.f.scanb[tid] - own;  // per-bin scatter cursor
        __syncthreads();
        // ---- scatter original indices into binned order ----
#pragma unroll
        for (int p = 0; p < 8; ++p) {
            const int i0 = 2 * (tid + p * 512);
            int pos0 = atomicAdd(&sm.f.hist[mybin[2 * p]], 1);
            sm.f.sidx[pos0] = i0;
            int pos1 = atomicAdd(&sm.f.hist[mybin[2 * p + 1]], 1);
            sm.f.sidx[pos1] = i0 + 1;
        }
        __syncthreads();

        // ---- gather this thread's 16-point chunk (packed pairs) + bbox ----
        vfloat2 px[8], py[8], pz[8], dist[8];
        int idxr[16];
#pragma unroll
        for (int p = 0; p < 8; ++p) {
            const int j0 = sm.f.sidx[tid * 16 + 2 * p];
            const int j1 = sm.f.sidx[tid * 16 + 2 * p + 1];
            idxr[2 * p] = j0;
            idxr[2 * p + 1] = j1;
            px[p] = (vfloat2){sm.f.sx[j0], sm.f.sx[j1]};
            py[p] = (vfloat2){sm.f.sy[j0], sm.f.sy[j1]};
            pz[p] = (vfloat2){sm.f.sz[j0], sm.f.sz[j1]};
            dist[p] = (vfloat2){INFINITY, INFINITY};
        }
        float blx = fminf(px[0].x, px[0].y), bhx = fmaxf(px[0].x, px[0].y);
        float bly = fminf(py[0].x, py[0].y), bhy = fmaxf(py[0].x, py[0].y);
        float blz = fminf(pz[0].x, pz[0].y), bhz = fmaxf(pz[0].x, pz[0].y);
#pragma unroll
        for (int p = 1; p < 8; ++p) {
            blx = fminf(blx, fminf(px[p].x, px[p].y));
            bhx = fmaxf(bhx, fmaxf(px[p].x, px[p].y));
            bly = fminf(bly, fminf(py[p].x, py[p].y));
            bhy = fmaxf(bhy, fmaxf(py[p].x, py[p].y));
            blz = fminf(blz, fminf(pz[p].x, pz[p].y));
            bhz = fmaxf(bhz, fmaxf(pz[p].x, pz[p].y));
        }

        float cmax = INFINITY;  // exact max of this chunk's current dists
        int cidx = idxr[0];     // smallest original index achieving cmax
        int far = 0;
        for (int t = 0; t < MM; ++t) {
            if (tid == 0) {
                sm.f.sfps[t] = far;               // LDS only: no vmcnt at barrier
                sm.f.red3[(t + 1) % 3] = 0ull;    // pre-reset next slot (its previous
            }                                     // readers all passed barrier t-1)
            const float cx = sm.f.sx[far];
            const float cy = sm.f.sy[far];
            const float cz = sm.f.sz[far];

            // Lower bound on d^2(c, bbox) via clamp (v_med3). 0.999f margin >>
            // f32 rounding slack (~1.5e-6 rel) between this bound and the exact
            // per-point pipeline, so skipping is guaranteed a value-exact no-op.
            float qx = cx - fminf(fmaxf(cx, blx), bhx);
            float qy = cy - fminf(fmaxf(cy, bly), bhy);
            float qz = cz - fminf(fmaxf(cz, blz), bhz);
            float bound = (qx * qx + qy * qy) + qz * qz;
            const bool act = !(bound * 0.999f >= cmax);
            if (act) {  // per-lane predication; compiler wave-skips via execz
                const vfloat2 cx2 = {cx, cx};
                const vfloat2 cy2 = {cy, cy};
                const vfloat2 cz2 = {cz, cz};
                float mv = -1.0f;
#pragma unroll
                for (int p = 0; p < 8; ++p) {
                    vfloat2 dx = px[p] - cx2;   // v_pk_add_f32
                    vfloat2 dy = py[p] - cy2;
                    vfloat2 dz = pz[p] - cz2;
                    vfloat2 m1 = dx * dx;       // v_pk_mul_f32
                    vfloat2 m2 = dy * dy;
                    vfloat2 m3 = dz * dz;
                    vfloat2 s = (m1 + m2) + m3; // matches reference order
                    vfloat2 nd;
                    nd.x = fminf(dist[p].x, s.x);
                    nd.y = fminf(dist[p].y, s.y);
                    dist[p] = nd;
                    mv = fmaxf(fmaxf(mv, nd.x), nd.y);  // -> v_max3_f32
                }
                // smallest ORIGINAL index among chunk maxima (binned != idx order)
                int mi = 0x7FFFFFFF;
#pragma unroll
                for (int p = 0; p < 8; ++p) {
                    mi = min(mi, (dist[p].x == mv) ? idxr[2 * p] : 0x7FFFFFFF);
                    mi = min(mi, (dist[p].y == mv) ? idxr[2 * p + 1] : 0x7FFFFFFF);
                }
                cmax = mv;
                cidx = mi;
            }

            // ---- wave reduce (unconditional, all waves): u32 max of dist bits
            //      (== f32 order, nonneg), then u32 min of tie-masked idx ----
            unsigned mvb = __float_as_uint(cmax);
            mvb = dpp_max_u32<0x111>(mvb);  // row_shr:1
            mvb = dpp_max_u32<0x112>(mvb);  // row_shr:2
            mvb = dpp_max_u32<0x114>(mvb);  // row_shr:4
            mvb = dpp_max_u32<0x118>(mvb);  // row_shr:8
            mvb = dpp_max_u32<0x142>(mvb);  // row_bcast15
            mvb = dpp_max_u32<0x143>(mvb);  // row_bcast31 -> lane 63 has wave max
            const unsigned wmax = (unsigned)__builtin_amdgcn_readlane((int)mvb, 63);
            unsigned midx = (__float_as_uint(cmax) == wmax) ? (unsigned)cidx : 0x7FFFFFFFu;
            midx = dpp_min_u32<0x111>(midx);
            midx = dpp_min_u32<0x112>(midx);
            midx = dpp_min_u32<0x114>(midx);
            midx = dpp_min_u32<0x118>(midx);
            midx = dpp_min_u32<0x142>(midx);
            midx = dpp_min_u32<0x143>(midx);  // lane 63 has wave arg-min index
            if (lane == 63) {
                // pack (value, ~idx): u64 max => largest value, ties -> smallest idx.
                // key is always > 0 (~midx >= 0xFFFFE000), so the 0-reset never wins.
                unsigned long long key =
                    ((unsigned long long)wmax << 32) | (unsigned)(~midx);
                atomicMax(&sm.f.red3[t % 3], key);  // ds_max_u64, 8 writers
            }
            __syncthreads();
            far = (int)(~(unsigned)sm.f.red3[t % 3]);  // one 8B LDS broadcast read
        }
        __syncthreads();
        // coalesced dump of the selected indices
        for (int t = tid; t < MM; t += 512) fps_store[t] = sm.f.sfps[t];
    }
}

// ---------------- merged ball-query + gather-max: one wave per query ----------------
// bq phase finds up to 32 in-radius indices (kept in LDS, no global round
// trip) and emits x_out; gather phase max-reduces g over those indices
// (lane = output channel). Removes the sub_idx workspace traffic and one
// kernel launch gap.
__global__ __launch_bounds__(256) void bqgather_kernel(const float* __restrict__ x,
                                                       const int* __restrict__ fps_idx,
                                                       const float* __restrict__ g,
                                                       float* __restrict__ xout,
                                                       float* __restrict__ fout) {
    const float R2 = (float)(0.4 * 0.4);  // match python double product -> f32 cast
    __shared__ int sidl[4][KK];           // per-wave found indices
    int gw = (int)((blockIdx.x * 256 + threadIdx.x) >> 6);
    const int lane = threadIdx.x & 63;
    const int wvl = threadIdx.x >> 6;
    gw = __builtin_amdgcn_readfirstlane(gw);
    const int b = gw >> 11;
    const int m = gw & (MM - 1);
    const float* xb = x + (size_t)b * 3 * NN;

    const int ctr = fps_idx[gw];
    const float cx = xb[ctr];
    const float cy = xb[NN + ctr];
    const float cz = xb[2 * NN + ctr];

    int found = 0;
    int first = 0;
    float mx = -INFINITY, my = -INFINITY, mz = -INFINITY;

    for (int base = 0; base < NN; base += 64) {
        const int i = base + lane;
        const float xx = xb[i];
        const float yy = xb[NN + i];
        const float zz = xb[2 * NN + i];
        const float d2 = sqdist_exact(xx, yy, zz, cx, cy, cz);
        const bool q = d2 < R2;
        const unsigned long long mask = __ballot(q);
        if (q) {
            int pos = found + (int)__popcll(mask & ((1ull << lane) - 1ull));
            if (pos < KK) {
                sidl[wvl][pos] = i;
                mx = fmaxf(mx, xx);
                my = fmaxf(my, yy);
                mz = fmaxf(mz, zz);
            }
        }
        if (found == 0 && mask != 0ull) first = base + (int)__builtin_ctzll(mask);
        found += (int)__popcll(mask);
        if (found >= KK) break;
    }
    if (found < KK) {
        if (lane < KK - found) sidl[wvl][found + lane] = first;  // pad with first found
    }
#pragma unroll
    for (int off = 32; off >= 1; off >>= 1) {
        mx = fmaxf(mx, __shfl_xor(mx, off, 64));
        my = fmaxf(my, __shfl_xor(my, off, 64));
        mz = fmaxf(mz, __shfl_xor(mz, off, 64));
    }
    if (lane == 0) {
        xout[(size_t)b * 3 * MM + 0 * MM + m] = mx;
        xout[(size_t)b * 3 * MM + 1 * MM + m] = my;
        xout[(size_t)b * 3 * MM + 2 * MM + m] = mz;
    }
    __syncthreads();  // all waves done writing their sidl row

    const float* gb = g + ((size_t)b << 19);
    float acc = -INFINITY;
#pragma unroll
    for (int j = 0; j < KK; ++j) {
        const int id = sidl[wvl][j];
        acc = fmaxf(acc, gb[(size_t)id * 64 + lane]);
    }
    fout[((size_t)b << 17) + ((size_t)lane << 11) + m] = acc;
}

extern "C" void kernel_launch(void* const* d_in, const int* in_sizes, int n_in,
                              void* d_out, int out_size, void* d_ws, size_t ws_size,
                              hipStream_t stream) {
    const float* x = (const float*)d_in[0];        // (8,3,8192)
    const float* feature = (const float*)d_in[1];  // (8,64,8192)
    const float* weight = (const float*)d_in[2];   // (64,64)
    // d_in[3] = num_pool (=2048), hard-coded as MM

    float* out = (float*)d_out;
    float* xout = out;                  // (8,3,2048)
    float* fout = out + BB * 3 * MM;    // (8,64,2048)

    char* ws = (char*)d_ws;
    int* fps_idx = (int*)ws;                                       // 64 KB
    float* g = (float*)(ws + (size_t)BB * MM * 4 + (size_t)BB * MM * KK * 4);  // 16 MB

    // blocks 0..7: FPS (one per batch); blocks 8..135: transform (concurrent
    // on otherwise-idle CUs — fps holds only 8 of 256 CUs).
    fps_transform_kernel<<<BB + (BB * NN) / 512, 512, 0, stream>>>(
        x, fps_idx, feature, weight, g);
    bqgather_kernel<<<(BB * MM * 64) / 256, 256, 0, stream>>>(x, fps_idx, g, xout, fout);
}